// Round 1
// baseline (155.664 us; speedup 1.0000x reference)
//
#include <hip/hip_runtime.h>
#include <math.h>

#define KC 33            // clusters
#define ED 32            // embedding dim
#define KE (KC * ED)     // 1056
#define PAD 33           // padded leading dim for LDS tiles

// accum geometry
#define BPB_A 64         // blocks per batch
#define TPA 128          // points per staged tile
#define NSLOT 8          // half-waves per 256-thread block
// hinge geometry
#define BPB_H 128
#define TPH 256          // points per tile (1 per thread)

// ws layout (floats): sums[B*KE] | counts[B*KC] | var[B] | done[B] (uint bits)

__global__ void k_zero(float* __restrict__ ws, int n, float* __restrict__ out) {
    int i = blockIdx.x * blockDim.x + threadIdx.x;
    if (i < n) ws[i] = 0.f;
    if (i == 0) out[0] = 0.f;
}

// Pass 1: per-(b,k) embedding sums + label histogram (k_hist fused in — the
// labels are already read here for s_lab, so the separate 2 MiB hist pass is
// pure waste). Register-prefetch pipelined staging into a +33-padded LDS tile;
// half-wave per point (lane=dim) non-atomic RMW into per-half-wave private
// copies (bank = e for both halves: 2-way = free).
__global__ __launch_bounds__(256) void k_accum(const float* __restrict__ emb,
                                               const int* __restrict__ lab,
                                               float* __restrict__ sums,
                                               float* __restrict__ counts, int N) {
    __shared__ float s_tile[TPA * PAD];      // 16.9 KB
    __shared__ float s_priv[NSLOT * KE];     // 33 KB
    __shared__ int   s_lab[TPA];
    __shared__ float s_hist[2 * KC];         // waves 0,1 stage labels (t < 128)
    int t = threadIdx.x;
    for (int i = t; i < NSLOT * KE; i += 256) s_priv[i] = 0.f;
    if (t < 2 * KC) s_hist[t] = 0.f;

    int b     = blockIdx.x / BPB_A;
    int blk   = blockIdx.x % BPB_A;
    int chunk = N / BPB_A;                   // 1024
    int e     = t & 31;
    int slot  = t >> 5;
    size_t pbase = (size_t)b * N + (size_t)blk * chunk;
    const int NT = chunk / TPA;              // 8 tiles

    // prefetch tile 0
    const float4* g4 = (const float4*)(emb + pbase * ED);
    float4 r0 = g4[t], r1 = g4[t + 256], r2 = g4[t + 512], r3 = g4[t + 768];
    int rl = 0;
    if (t < TPA) rl = lab[pbase + t];
    __syncthreads();                          // priv + hist init done

    for (int tb = 0; tb < NT; tb++) {
        // unpack staged registers into padded tile
        {
            int f, p, m;
            f = t;        p = f >> 3; m = (f & 7) * 4;
            { float* d = &s_tile[PAD * p + m]; d[0]=r0.x; d[1]=r0.y; d[2]=r0.z; d[3]=r0.w; }
            f = t + 256;  p = f >> 3; m = (f & 7) * 4;
            { float* d = &s_tile[PAD * p + m]; d[0]=r1.x; d[1]=r1.y; d[2]=r1.z; d[3]=r1.w; }
            f = t + 512;  p = f >> 3; m = (f & 7) * 4;
            { float* d = &s_tile[PAD * p + m]; d[0]=r2.x; d[1]=r2.y; d[2]=r2.z; d[3]=r2.w; }
            f = t + 768;  p = f >> 3; m = (f & 7) * 4;
            { float* d = &s_tile[PAD * p + m]; d[0]=r3.x; d[1]=r3.y; d[2]=r3.z; d[3]=r3.w; }
        }
        if (t < TPA) {
            s_lab[t] = rl;
            atomicAdd(&s_hist[(t >> 6) * KC + rl], 1.f);   // fused histogram
        }
        __syncthreads();

        // prefetch next tile while computing this one
        if (tb + 1 < NT) {
            const float4* gn = (const float4*)(emb + (pbase + (size_t)(tb + 1) * TPA) * ED);
            r0 = gn[t]; r1 = gn[t + 256]; r2 = gn[t + 512]; r3 = gn[t + 768];
            if (t < TPA) rl = lab[pbase + (size_t)(tb + 1) * TPA + t];
        }

        float* priv = &s_priv[slot * KE];
#pragma unroll
        for (int st = 0; st < TPA / NSLOT; st++) {
            int pt = st * NSLOT + slot;
            float x = s_tile[pt * PAD + e];
            int   k = s_lab[pt];
            priv[k * ED + e] += x;           // private: no atomic; bank=e: free
        }
        __syncthreads();
    }

    for (int i = t; i < KE; i += 256) {
        float v = 0.f;
#pragma unroll
        for (int s = 0; s < NSLOT; s++) v += s_priv[s * KE + i];
        atomicAdd(&sums[(size_t)b * KE + i], v);
    }
    if (t < KC)
        atomicAdd(&counts[b * KC + t], s_hist[t] + s_hist[KC + t]);
}

// Pass 2: lane-owns-point hinge, registers only (pass-2 embeddings are
// L3-resident after pass 1, so strided per-thread float4 loads are cheap and
// the LDS transpose tile + per-tile barriers are pure overhead). The last
// block per batch (done-counter) runs the epilogue in-place (k_final fused).
#define D2ACC(v, o) { float d_;                          \
    d_ = (v).x - cr[(o)];     d2 = fmaf(d_, d_, d2);     \
    d_ = (v).y - cr[(o) + 1]; d2 = fmaf(d_, d_, d2);     \
    d_ = (v).z - cr[(o) + 2]; d2 = fmaf(d_, d_, d2);     \
    d_ = (v).w - cr[(o) + 3]; d2 = fmaf(d_, d_, d2); }

__global__ __launch_bounds__(256) void k_hinge(const float* __restrict__ emb,
                                               const int* __restrict__ lab,
                                               const float* __restrict__ sums,
                                               const float* __restrict__ counts,
                                               float* __restrict__ var,
                                               unsigned* __restrict__ done,
                                               float* __restrict__ out,
                                               int N, int B) {
    __shared__ float s_ctr[KC * PAD];        // 4.3 KB, padded
    __shared__ float s_cnt[KC];
    __shared__ float s_inv[KC];
    __shared__ int   s_prs[KC];
    __shared__ float s_reg[KC];
    __shared__ float s_red[4];
    __shared__ float s_red2[256];
    __shared__ int   s_last;
    int t     = threadIdx.x;
    int b     = blockIdx.x / BPB_H;
    int blk   = blockIdx.x % BPB_H;
    int chunk = N / BPB_H;                   // 512
    size_t pbase = (size_t)b * N + (size_t)blk * chunk;
    const int NT = chunk / TPH;              // 2

    // prefetch this thread's point 0 (issues before the centers compute, so
    // HBM/L3 latency hides under the sums read + divide)
    const float4* g0 = (const float4*)(emb + (pbase + t) * ED);
    float4 x0 = g0[0], x1 = g0[1], x2 = g0[2], x3 = g0[3],
           x4 = g0[4], x5 = g0[5], x6 = g0[6], x7 = g0[7];
    int rk = lab[pbase + t];

    if (t < KC) {
        float c = counts[b * KC + t];
        s_cnt[t] = fmaxf(c, 1.f);
        int p = (t > 0 && c > 0.f) ? 1 : 0;
        s_inv[t] = p ? 1.f / fmaxf(c, 1.f) : 0.f;
        s_prs[t] = p;
    }
    __syncthreads();
    for (int i = t; i < KE; i += 256) {
        int k = i >> 5, e = i & 31;
        s_ctr[k * PAD + e] = sums[(size_t)b * KE + i] / s_cnt[k];
    }
    __syncthreads();

    float hs = 0.f;
    for (int tb = 0; tb < NT; tb++) {
        float4 y0, y1, y2, y3, y4, y5, y6, y7;
        int nk = 0;
        if (tb + 1 < NT) {                   // prefetch next point
            const float4* gn = (const float4*)(emb + (pbase + (size_t)(tb + 1) * TPH + t) * ED);
            y0 = gn[0]; y1 = gn[1]; y2 = gn[2]; y3 = gn[3];
            y4 = gn[4]; y5 = gn[5]; y6 = gn[6]; y7 = gn[7];
            nk = lab[pbase + (size_t)(tb + 1) * TPH + t];
        }
        const float* cr = &s_ctr[rk * PAD];
        float iv = s_inv[rk];
        float d2 = 0.f;
        D2ACC(x0, 0)  D2ACC(x1, 4)  D2ACC(x2, 8)  D2ACC(x3, 12)
        D2ACC(x4, 16) D2ACC(x5, 20) D2ACC(x6, 24) D2ACC(x7, 28)
        float dist = sqrtf(fmaxf(d2, 1e-12f));
        hs += fmaxf(dist - 0.5f, 0.f) * iv;
        if (tb + 1 < NT) {
            x0 = y0; x1 = y1; x2 = y2; x3 = y3;
            x4 = y4; x5 = y5; x6 = y6; x7 = y7;
            rk = nk;
        }
    }

    // block reduction of hs (one value per thread)
    hs += __shfl_xor(hs, 1);  hs += __shfl_xor(hs, 2);  hs += __shfl_xor(hs, 4);
    hs += __shfl_xor(hs, 8);  hs += __shfl_xor(hs, 16); hs += __shfl_xor(hs, 32);
    if ((t & 63) == 0) s_red[t >> 6] = hs;
    __syncthreads();
    if (t == 0) {
        atomicAdd(&var[b], s_red[0] + s_red[1] + s_red[2] + s_red[3]);
        __threadfence();                     // release var add before done++
        unsigned old = atomicAdd(&done[b], 1u);
        s_last = (old == (unsigned)(BPB_H - 1)) ? 1 : 0;
    }
    __syncthreads();
    if (!s_last) return;

    // ---- epilogue (last block of this batch; centers already in LDS) ----
    __threadfence();                         // acquire other blocks' var adds
    if (t < KC) {
        float n2 = 0.f;
        for (int e2 = 0; e2 < ED; e2++) { float c = s_ctr[t * PAD + e2]; n2 += c * c; }
        s_reg[t] = s_prs[t] ? sqrtf(fmaxf(n2, 1e-12f)) : 0.f;
    }
    __syncthreads();

    float psum = 0.f;
    for (int q = t; q < KC * KC; q += 256) {
        int i = q / KC, j = q % KC;
        if (i < j && s_prs[i] && s_prs[j]) {
            float d2 = 0.f;
            for (int e2 = 0; e2 < ED; e2++) {
                float d = s_ctr[i * PAD + e2] - s_ctr[j * PAD + e2];
                d2 += d * d;
            }
            float cd = sqrtf(fmaxf(d2, 1e-12f));
            psum += fmaxf(3.0f - cd, 0.f);   // 2*DELTA_D = 3.0
        }
    }
    s_red2[t] = psum;
    __syncthreads();
    for (int s = 128; s > 0; s >>= 1) {
        if (t < s) s_red2[t] += s_red2[t + s];
        __syncthreads();
    }

    if (t == 0) {
        float vb = atomicAdd(&var[b], 0.f);  // device-scope coherent read
        float reg = 0.f; int n = 0;
        for (int k = 0; k < KC; k++) { reg += s_reg[k]; n += s_prs[k]; }
        float nf = (float)n;
        float variance_term = vb / fmaxf(nf, 1.f);
        float npairs = nf * (nf - 1.f) * 0.5f;
        float distance_term = s_red2[0] / fmaxf(npairs, 1.f);
        float reg_term = reg / fmaxf(nf, 1.f);
        float pb = variance_term + distance_term + 0.001f * reg_term;
        if (n == 0) pb = 0.f;
        atomicAdd(out, pb / (float)B);
    }
}

extern "C" void kernel_launch(void* const* d_in, const int* in_sizes, int n_in,
                              void* d_out, int out_size, void* d_ws, size_t ws_size,
                              hipStream_t stream) {
    const float* emb = (const float*)d_in[0];
    const int*   lab = (const int*)d_in[1];
    float* out = (float*)d_out;

    const int B = 8;
    const int N = in_sizes[1] / B;   // 65536

    float*    sums   = (float*)d_ws;
    float*    counts = sums + (size_t)B * KE;
    float*    var    = counts + (size_t)B * KC;
    unsigned* done   = (unsigned*)(var + B);

    int zn = B * KE + B * KC + B + B;
    k_zero<<<(zn + 255) / 256, 256, 0, stream>>>((float*)d_ws, zn, out);
    k_accum<<<B * BPB_A, 256, 0, stream>>>(emb, lab, sums, counts, N);
    k_hinge<<<B * BPB_H, 256, 0, stream>>>(emb, lab, sums, counts, var, done, out, N, B);
}

// Round 2
// 147.888 us; speedup vs baseline: 1.0526x; 1.0526x over previous
//
#include <hip/hip_runtime.h>
#include <math.h>

#define KC 33            // clusters
#define ED 32            // embedding dim
#define KE (KC * ED)     // 1056
#define PAD 33           // padded leading dim for LDS tiles

// accum geometry
#define BPB_A 64         // blocks per batch
#define TPA 128          // points per staged tile
#define NSLOT 8          // half-waves per 256-thread block
// hinge geometry
#define BPB_H 128
#define TPH 256          // points per staged tile (1 per thread)

// ws layout (floats): sums[B*KE] | counts[B*KC] | var[B] | done[B] (uint bits)

__global__ void k_zero(float* __restrict__ ws, int n, float* __restrict__ out) {
    int i = blockIdx.x * blockDim.x + threadIdx.x;
    if (i < n) ws[i] = 0.f;
    if (i == 0) out[0] = 0.f;
}

// Pass 1: per-(b,k) embedding sums + fused label histogram (labels are already
// read here for s_lab, so a separate hist pass is pure waste). Register-prefetch
// pipelined staging into a +33-padded LDS tile; half-wave per point (lane=dim)
// non-atomic RMW into per-half-wave private copies (bank = e both halves: free).
__global__ __launch_bounds__(256) void k_accum(const float* __restrict__ emb,
                                               const int* __restrict__ lab,
                                               float* __restrict__ sums,
                                               float* __restrict__ counts, int N) {
    __shared__ float s_tile[TPA * PAD];      // 16.9 KB
    __shared__ float s_priv[NSLOT * KE];     // 33 KB
    __shared__ int   s_lab[TPA];
    __shared__ float s_hist[2 * KC];
    int t = threadIdx.x;
    for (int i = t; i < NSLOT * KE; i += 256) s_priv[i] = 0.f;
    if (t < 2 * KC) s_hist[t] = 0.f;

    int b     = blockIdx.x / BPB_A;
    int blk   = blockIdx.x % BPB_A;
    int chunk = N / BPB_A;                   // 1024
    int e     = t & 31;
    int slot  = t >> 5;
    size_t pbase = (size_t)b * N + (size_t)blk * chunk;
    const int NT = chunk / TPA;              // 8 tiles

    // prefetch tile 0
    const float4* g4 = (const float4*)(emb + pbase * ED);
    float4 r0 = g4[t], r1 = g4[t + 256], r2 = g4[t + 512], r3 = g4[t + 768];
    int rl = 0;
    if (t < TPA) rl = lab[pbase + t];
    __syncthreads();                          // priv + hist init done

    for (int tb = 0; tb < NT; tb++) {
        // unpack staged registers into padded tile
        {
            int f, p, m;
            f = t;        p = f >> 3; m = (f & 7) * 4;
            { float* d = &s_tile[PAD * p + m]; d[0]=r0.x; d[1]=r0.y; d[2]=r0.z; d[3]=r0.w; }
            f = t + 256;  p = f >> 3; m = (f & 7) * 4;
            { float* d = &s_tile[PAD * p + m]; d[0]=r1.x; d[1]=r1.y; d[2]=r1.z; d[3]=r1.w; }
            f = t + 512;  p = f >> 3; m = (f & 7) * 4;
            { float* d = &s_tile[PAD * p + m]; d[0]=r2.x; d[1]=r2.y; d[2]=r2.z; d[3]=r2.w; }
            f = t + 768;  p = f >> 3; m = (f & 7) * 4;
            { float* d = &s_tile[PAD * p + m]; d[0]=r3.x; d[1]=r3.y; d[2]=r3.z; d[3]=r3.w; }
        }
        if (t < TPA) {
            s_lab[t] = rl;
            atomicAdd(&s_hist[(t >> 6) * KC + rl], 1.f);   // fused histogram
        }
        __syncthreads();

        // prefetch next tile while computing this one
        if (tb + 1 < NT) {
            const float4* gn = (const float4*)(emb + (pbase + (size_t)(tb + 1) * TPA) * ED);
            r0 = gn[t]; r1 = gn[t + 256]; r2 = gn[t + 512]; r3 = gn[t + 768];
            if (t < TPA) rl = lab[pbase + (size_t)(tb + 1) * TPA + t];
        }

        float* priv = &s_priv[slot * KE];
#pragma unroll
        for (int st = 0; st < TPA / NSLOT; st++) {
            int pt = st * NSLOT + slot;
            float x = s_tile[pt * PAD + e];
            int   k = s_lab[pt];
            priv[k * ED + e] += x;           // private: no atomic; bank=e: free
        }
        __syncthreads();
    }

    for (int i = t; i < KE; i += 256) {
        float v = 0.f;
#pragma unroll
        for (int s = 0; s < NSLOT; s++) v += s_priv[s * KE + i];
        atomicAdd(&sums[(size_t)b * KE + i], v);
    }
    if (t < KC)
        atomicAdd(&counts[b * KC + t], s_hist[t] + s_hist[KC + t]);
}

// Pass 2: lane-owns-point hinge with coalesced register-prefetch -> padded LDS
// tile staging (round-0 structure: each wave load instruction covers one
// contiguous 1KB segment; the per-thread strided variant was latency-bound at
// 64 cache lines per instruction). Last block per batch (done-counter) runs the
// epilogue in place (k_final fused; centers already in LDS).
__global__ __launch_bounds__(256) void k_hinge(const float* __restrict__ emb,
                                               const int* __restrict__ lab,
                                               const float* __restrict__ sums,
                                               const float* __restrict__ counts,
                                               float* __restrict__ var,
                                               unsigned* __restrict__ done,
                                               float* __restrict__ out,
                                               int N, int B) {
    __shared__ float s_tile[TPH * PAD];      // 33.8 KB
    __shared__ float s_ctr[KC * PAD];        // 4.3 KB, padded
    __shared__ float s_cnt[KC];
    __shared__ float s_inv[KC];
    __shared__ int   s_prs[KC];
    __shared__ float s_reg[KC];
    __shared__ int   s_lab[TPH];
    __shared__ float s_red[4];
    __shared__ float s_red2[256];
    __shared__ int   s_last;
    int t     = threadIdx.x;
    int b     = blockIdx.x / BPB_H;
    int blk   = blockIdx.x % BPB_H;
    int chunk = N / BPB_H;                   // 512
    size_t pbase = (size_t)b * N + (size_t)blk * chunk;
    const int NT = chunk / TPH;              // 2 tiles

    // prefetch tile 0 (8 float4 per thread = 1 point per thread, coalesced)
    const float4* g4 = (const float4*)(emb + pbase * ED);
    float4 r0 = g4[t],        r1 = g4[t + 256],  r2 = g4[t + 512],  r3 = g4[t + 768];
    float4 r4 = g4[t + 1024], r5 = g4[t + 1280], r6 = g4[t + 1536], r7 = g4[t + 1792];
    int rl = lab[pbase + t];

    if (t < KC) {
        float c = counts[b * KC + t];
        s_cnt[t] = fmaxf(c, 1.f);
        int p = (t > 0 && c > 0.f) ? 1 : 0;
        s_inv[t] = p ? 1.f / fmaxf(c, 1.f) : 0.f;
        s_prs[t] = p;
    }
    __syncthreads();
    for (int i = t; i < KE; i += 256) {
        int k = i >> 5, e = i & 31;
        s_ctr[k * PAD + e] = sums[(size_t)b * KE + i] / s_cnt[k];
    }

    float hs = 0.f;
    for (int tb = 0; tb < NT; tb++) {
        {
            int f, p, m;
            f = t;         p = f >> 3; m = (f & 7) * 4;
            { float* d = &s_tile[PAD * p + m]; d[0]=r0.x; d[1]=r0.y; d[2]=r0.z; d[3]=r0.w; }
            f = t + 256;   p = f >> 3; m = (f & 7) * 4;
            { float* d = &s_tile[PAD * p + m]; d[0]=r1.x; d[1]=r1.y; d[2]=r1.z; d[3]=r1.w; }
            f = t + 512;   p = f >> 3; m = (f & 7) * 4;
            { float* d = &s_tile[PAD * p + m]; d[0]=r2.x; d[1]=r2.y; d[2]=r2.z; d[3]=r2.w; }
            f = t + 768;   p = f >> 3; m = (f & 7) * 4;
            { float* d = &s_tile[PAD * p + m]; d[0]=r3.x; d[1]=r3.y; d[2]=r3.z; d[3]=r3.w; }
            f = t + 1024;  p = f >> 3; m = (f & 7) * 4;
            { float* d = &s_tile[PAD * p + m]; d[0]=r4.x; d[1]=r4.y; d[2]=r4.z; d[3]=r4.w; }
            f = t + 1280;  p = f >> 3; m = (f & 7) * 4;
            { float* d = &s_tile[PAD * p + m]; d[0]=r5.x; d[1]=r5.y; d[2]=r5.z; d[3]=r5.w; }
            f = t + 1536;  p = f >> 3; m = (f & 7) * 4;
            { float* d = &s_tile[PAD * p + m]; d[0]=r6.x; d[1]=r6.y; d[2]=r6.z; d[3]=r6.w; }
            f = t + 1792;  p = f >> 3; m = (f & 7) * 4;
            { float* d = &s_tile[PAD * p + m]; d[0]=r7.x; d[1]=r7.y; d[2]=r7.z; d[3]=r7.w; }
        }
        s_lab[t] = rl;
        __syncthreads();

        if (tb + 1 < NT) {
            const float4* gn = (const float4*)(emb + (pbase + (size_t)(tb + 1) * TPH) * ED);
            r0 = gn[t];        r1 = gn[t + 256];  r2 = gn[t + 512];  r3 = gn[t + 768];
            r4 = gn[t + 1024]; r5 = gn[t + 1280]; r6 = gn[t + 1536]; r7 = gn[t + 1792];
            rl = lab[pbase + (size_t)(tb + 1) * TPH + t];
        }

        int   k  = s_lab[t];
        float iv = s_inv[k];
        const float* xr = &s_tile[t * PAD];
        const float* cr = &s_ctr[k * PAD];
        float d2 = 0.f;
#pragma unroll
        for (int j = 0; j < ED; j++) {
            float d = xr[j] - cr[j];
            d2 = fmaf(d, d, d2);
        }
        float dist = sqrtf(fmaxf(d2, 1e-12f));
        hs += fmaxf(dist - 0.5f, 0.f) * iv;
        __syncthreads();
    }

    // block reduction of hs (one value per thread)
    hs += __shfl_xor(hs, 1);  hs += __shfl_xor(hs, 2);  hs += __shfl_xor(hs, 4);
    hs += __shfl_xor(hs, 8);  hs += __shfl_xor(hs, 16); hs += __shfl_xor(hs, 32);
    if ((t & 63) == 0) s_red[t >> 6] = hs;
    __syncthreads();
    if (t == 0) {
        atomicAdd(&var[b], s_red[0] + s_red[1] + s_red[2] + s_red[3]);
        __threadfence();                     // release var add before done++
        unsigned old = atomicAdd(&done[b], 1u);
        s_last = (old == (unsigned)(BPB_H - 1)) ? 1 : 0;
    }
    __syncthreads();
    if (!s_last) return;

    // ---- epilogue (last block of this batch; centers already in LDS) ----
    __threadfence();                         // acquire other blocks' var adds
    if (t < KC) {
        float n2 = 0.f;
        for (int e2 = 0; e2 < ED; e2++) { float c = s_ctr[t * PAD + e2]; n2 += c * c; }
        s_reg[t] = s_prs[t] ? sqrtf(fmaxf(n2, 1e-12f)) : 0.f;
    }
    __syncthreads();

    float psum = 0.f;
    for (int q = t; q < KC * KC; q += 256) {
        int i = q / KC, j = q % KC;
        if (i < j && s_prs[i] && s_prs[j]) {
            float d2 = 0.f;
            for (int e2 = 0; e2 < ED; e2++) {
                float d = s_ctr[i * PAD + e2] - s_ctr[j * PAD + e2];
                d2 += d * d;
            }
            float cd = sqrtf(fmaxf(d2, 1e-12f));
            psum += fmaxf(3.0f - cd, 0.f);   // 2*DELTA_D = 3.0
        }
    }
    s_red2[t] = psum;
    __syncthreads();
    for (int s = 128; s > 0; s >>= 1) {
        if (t < s) s_red2[t] += s_red2[t + s];
        __syncthreads();
    }

    if (t == 0) {
        float vb = atomicAdd(&var[b], 0.f);  // device-scope coherent read
        float reg = 0.f; int n = 0;
        for (int k = 0; k < KC; k++) { reg += s_reg[k]; n += s_prs[k]; }
        float nf = (float)n;
        float variance_term = vb / fmaxf(nf, 1.f);
        float npairs = nf * (nf - 1.f) * 0.5f;
        float distance_term = s_red2[0] / fmaxf(npairs, 1.f);
        float reg_term = reg / fmaxf(nf, 1.f);
        float pb = variance_term + distance_term + 0.001f * reg_term;
        if (n == 0) pb = 0.f;
        atomicAdd(out, pb / (float)B);
    }
}

extern "C" void kernel_launch(void* const* d_in, const int* in_sizes, int n_in,
                              void* d_out, int out_size, void* d_ws, size_t ws_size,
                              hipStream_t stream) {
    const float* emb = (const float*)d_in[0];
    const int*   lab = (const int*)d_in[1];
    float* out = (float*)d_out;

    const int B = 8;
    const int N = in_sizes[1] / B;   // 65536

    float*    sums   = (float*)d_ws;
    float*    counts = sums + (size_t)B * KE;
    float*    var    = counts + (size_t)B * KC;
    unsigned* done   = (unsigned*)(var + B);

    int zn = B * KE + B * KC + B + B;
    k_zero<<<(zn + 255) / 256, 256, 0, stream>>>((float*)d_ws, zn, out);
    k_accum<<<B * BPB_A, 256, 0, stream>>>(emb, lab, sums, counts, N);
    k_hinge<<<B * BPB_H, 256, 0, stream>>>(emb, lab, sums, counts, var, done, out, N, B);
}